// Round 6
// baseline (1484.916 us; speedup 1.0000x reference)
//
#include <hip/hip_runtime.h>

// Problem: S=512, B=256, I=64, H=512, O=25.
// y depends only on batch row 255 -> compute only that row's recurrence.
//
// rnn_pre : xi[t][h] = x[t,255,:].W_ih[h,:] + b_ih[h] + b_hh[h]; re-inits the
//           exchange buffers (sign=1 = not-ready) every launch.
// rnn_seq : 512 sequential steps h = relu(xi_t + W_hh h_prev) on 16 blocks x
//           256 threads (32 rows/block, W_hh register-resident). Cross-block
//           exchange: PROVEN protocol -- 32-bit words, generation in the SIGN
//           BIT (relu => h>=0), double-buffered by s&1, phase=(s>>1)&1;
//           barrier-A ordering carries the skew<2 invariant. Relaxed
//           agent-scope atomics only.
//           Round-6 changes (on top of the 637us round-5 kernel):
//           (1) NO barrier B, NO h_l LDS: each thread polls its own 64-wide
//               FMA k-chunk (32 u64 agent loads, the proven primitive)
//               directly into the registers the FMA reads. Tag-strip is
//               folded into the FMA via the free abs() input modifier
//               (tagged word = +/-h with h>=0 -> |.| == h; -0.0 -> +0.0).
//               part[] is double-buffered by s&1 to close the one race
//               barrier B used to cover (next-iter partial overwrite vs
//               this-iter finalize read).
//           (2) producer store -> atomic_exchange (executes AT the coherence
//               point -> value visible on packet arrival, not on lazy write
//               drain).
//           (3) lgkm-only barrier A + adaptive per-thread poll delay D
//               (kept from round 5).
// rnn_post: y[t] = h_t . W2^T + b2 (512x25).
//
// Workspace: xh[512*512] (xi, progressively overwritten by hseq -- each block
// writes h only over its OWN already-consumed xi rows; strictly ordered),
// hg[2*512] exchange words.

#define S_ 512
#define B_ 256
#define I_ 64
#define H_ 512
#define O_ 25
#define G_ 16   // blocks in rnn_seq
#define R_ 32   // rows per block (H_/G_)

// Barrier with LDS-only drain: no vmcnt(0) -> exchange stores / poll loads /
// xi prefetch stay in flight across it. sched_barrier(0) fences compiler
// motion (rule #18).
static __device__ __forceinline__ void wg_barrier_lds() {
  __builtin_amdgcn_sched_barrier(0);
  asm volatile("s_waitcnt lgkmcnt(0)" ::: "memory");
  __builtin_amdgcn_s_barrier();
  __builtin_amdgcn_sched_barrier(0);
}

__global__ __launch_bounds__(256) void rnn_pre(
    const float* __restrict__ x, const float* __restrict__ W_ih,
    const float* __restrict__ b_ih, const float* __restrict__ b_hh,
    float* __restrict__ xh, unsigned* __restrict__ hg) {
  const int t = blockIdx.x;
  const int tid = threadIdx.x;
  const int o = blockIdx.y * 256 + tid;
  if (t == 0 && blockIdx.y == 0) {
    // re-init every launch: no reliance on workspace poison / prior state.
    hg[tid] = 0x80000000u;
    hg[tid + 256] = 0x80000000u;
    hg[tid + 512] = 0x80000000u;
    hg[tid + 768] = 0x80000000u;
  }
  __shared__ float xr[I_];
  if (tid < I_) xr[tid] = x[(t * B_ + (B_ - 1)) * I_ + tid];
  __syncthreads();
  float acc = b_ih[o] + b_hh[o];
  const float4* wp = (const float4*)(W_ih + o * I_);
#pragma unroll
  for (int j = 0; j < I_ / 4; ++j) {
    float4 w4 = wp[j];
    acc += w4.x * xr[4 * j] + w4.y * xr[4 * j + 1] + w4.z * xr[4 * j + 2] +
           w4.w * xr[4 * j + 3];
  }
  xh[t * H_ + o] = acc;
}

__global__ __launch_bounds__(256, 1) void rnn_seq(
    const float* __restrict__ W_hh, float* __restrict__ xh,
    unsigned* hg) {
  const int tid = threadIdx.x;
  const int b = blockIdx.x;
  const int r = tid & 31;        // row within block's 32 rows
  const int seg = tid >> 5;      // 0..7 : 64-wide k-chunk
  const int row = b * R_ + r;
  const int k0 = seg * 64;
  const int wave = tid >> 6;
  const int own_lo = b * R_;

  __shared__ __align__(16) float part[2][R_ * 4];  // dbuf by s&1; [row][wave]

  // W_hh register-resident: thread (r,seg) holds W_hh[row][k0..k0+63].
  float w[64];
  {
    const float4* wp = (const float4*)(W_hh + row * H_ + k0);
#pragma unroll
    for (int j = 0; j < 16; ++j) {
      float4 v = wp[j];
      w[4 * j] = v.x; w[4 * j + 1] = v.y;
      w[4 * j + 2] = v.z; w[4 * j + 3] = v.w;
    }
  }

  // h chunk register-resident as 32 tagged u64 pairs; h_{-1} = 0.
  unsigned long long hv[32];
#pragma unroll
  for (int j = 0; j < 32; ++j) hv[j] = 0ull;

  // xi for step 0; later steps prefetched during the poll phase.
  float xiv = (tid < R_) ? xh[own_lo + tid] : 0.0f;

  const unsigned long long sm = 0x8000000080000000ull;
  int D = 0;  // adaptive pre-poll delay, in s_sleep(1) (~64cy) units

  for (int s = 0; s < S_; ++s) {
    const int ps = s & 1;
    // ---- partial dot from register h (tag stripped via free |.|) ----
    float a0 = 0.f, a1 = 0.f, a2 = 0.f, a3 = 0.f;
#pragma unroll
    for (int j = 0; j < 16; ++j) {
      unsigned long long q0 = hv[2 * j], q1 = hv[2 * j + 1];
      float h0 = __uint_as_float((unsigned)q0);
      float h1 = __uint_as_float((unsigned)(q0 >> 32));
      float h2 = __uint_as_float((unsigned)q1);
      float h3 = __uint_as_float((unsigned)(q1 >> 32));
      a0 = fmaf(w[4 * j + 0], __builtin_fabsf(h0), a0);
      a1 = fmaf(w[4 * j + 1], __builtin_fabsf(h1), a1);
      a2 = fmaf(w[4 * j + 2], __builtin_fabsf(h2), a2);
      a3 = fmaf(w[4 * j + 3], __builtin_fabsf(h3), a3);
    }
    float acc = (a0 + a1) + (a2 + a3);
    acc += __shfl_xor(acc, 32, 64);  // fold seg pairs within the wave
    if ((tid & 32) == 0) part[ps][r * 4 + wave] = acc;
    wg_barrier_lds();  // barrier A: partials of step s visible

    const unsigned phase = (unsigned)((s >> 1) & 1);
    unsigned* buf = hg + ps * H_;

    if (tid < R_) {
      float4 p4 = *(const float4*)(&part[ps][tid * 4]);  // ds_read_b128
      float sum = p4.x + p4.y + p4.z + p4.w + xiv;
      float h = fmaxf(sum, 0.0f);
      // exchange via atomic swap: executes at the coherence point ->
      // visible on arrival (no lazy write-drain leg).
      (void)__hip_atomic_exchange(&buf[own_lo + tid],
                                  __float_as_uint(h) | (phase << 31),
                                  __ATOMIC_RELAXED, __HIP_MEMORY_SCOPE_AGENT);
      xh[s * H_ + own_lo + tid] = h;  // hseq (over consumed xi rows)
    }

    if (s == S_ - 1) break;  // no poll needed after last step

    // prefetch next step's xi (in flight across the poll; used >RTT later)
    if (tid < R_) xiv = xh[(s + 1) * H_ + own_lo + tid];

    // ---- poll own k-chunk into hv[] (32 u64 agent loads / iteration) ----
    for (int d = 0; d < D; ++d) __builtin_amdgcn_s_sleep(1);
    const unsigned long long* ap = (const unsigned long long*)buf + seg * 32;
    int n = 0;
    for (;;) {
      ++n;
#pragma unroll
      for (int j = 0; j < 32; ++j)
        hv[j] = __hip_atomic_load(ap + j, __ATOMIC_RELAXED,
                                  __HIP_MEMORY_SCOPE_AGENT);
      // readiness: all 64 sign bits == phase. 4 ILP chains, 8 deep.
      unsigned long long m0, m1, m2, m3;
      if (phase) {  // uniform branch: all signs must be 1 -> AND-reduce
        m0 = hv[0]; m1 = hv[1]; m2 = hv[2]; m3 = hv[3];
#pragma unroll
        for (int j = 1; j < 8; ++j) {
          m0 &= hv[4 * j + 0]; m1 &= hv[4 * j + 1];
          m2 &= hv[4 * j + 2]; m3 &= hv[4 * j + 3];
        }
        if ((~(m0 & m1 & m2 & m3) & sm) == 0ull) break;
      } else {      // all signs must be 0 -> OR-reduce
        m0 = hv[0]; m1 = hv[1]; m2 = hv[2]; m3 = hv[3];
#pragma unroll
        for (int j = 1; j < 8; ++j) {
          m0 |= hv[4 * j + 0]; m1 |= hv[4 * j + 1];
          m2 |= hv[4 * j + 2]; m3 |= hv[4 * j + 3];
        }
        if (((m0 | m1 | m2 | m3) & sm) == 0ull) break;
      }
    }
    // adapt: sampled too early -> push later; on time -> creep earlier.
    if (n > 1) {
      D += 8 * (n - 1);
      if (D > 48) D = 48;
    } else if ((s & 7) == 0 && D > 0) {
      --D;
    }
    // NO barrier B: part[] is double-buffered, h is register-private, and
    // barrier A + poll-completion ordering carry the skew<2 invariant.
  }
}

__global__ __launch_bounds__(256) void rnn_post(
    const float* __restrict__ hseq, const float* __restrict__ W2,
    const float* __restrict__ b2, float* __restrict__ y) {
  const int t = blockIdx.x;
  const int tid = threadIdx.x;
  __shared__ float hl[H_];
  __shared__ float part[256];
  for (int n = tid; n < H_; n += 256) hl[n] = hseq[t * H_ + n];
  __syncthreads();
  const int o = tid >> 3;
  const int seg = tid & 7;
  float acc = 0.0f;
  if (o < O_) {
    const float4* wp = (const float4*)(W2 + o * H_ + seg * 64);
    const float4* hp = (const float4*)(hl + seg * 64);
#pragma unroll
    for (int j = 0; j < 16; ++j) {
      float4 w4 = wp[j];
      float4 h4 = hp[j];
      acc += w4.x * h4.x + w4.y * h4.y + w4.z * h4.z + w4.w * h4.w;
    }
  }
  part[tid] = acc;
  __syncthreads();
  if (tid < O_) {
    float sum = 0.0f;
#pragma unroll
    for (int j = 0; j < 8; ++j) sum += part[tid * 8 + j];
    y[t * O_ + tid] = sum + b2[tid];
  }
}

extern "C" void kernel_launch(void* const* d_in, const int* in_sizes, int n_in,
                              void* d_out, int out_size, void* d_ws, size_t ws_size,
                              hipStream_t stream) {
  const float* x    = (const float*)d_in[0];
  const float* W_ih = (const float*)d_in[1];
  const float* W_hh = (const float*)d_in[2];
  const float* b_ih = (const float*)d_in[3];
  const float* b_hh = (const float*)d_in[4];
  const float* W2   = (const float*)d_in[5];
  const float* b2   = (const float*)d_in[6];
  float* y = (float*)d_out;

  float* xh = (float*)d_ws;                  // [512*512] xi -> hseq (aliased)
  unsigned* hg = (unsigned*)(xh + S_ * H_);  // [2*512] sign-tagged exchange

  rnn_pre<<<dim3(S_, 2), 256, 0, stream>>>(x, W_ih, b_ih, b_hh, xh, hg);
  rnn_seq<<<G_, 256, 0, stream>>>(W_hh, xh, hg);
  rnn_post<<<S_, 256, 0, stream>>>(xh, W2, b2, y);
}